// Round 10
// baseline (166.107 us; speedup 1.0000x reference)
//
#include <hip/hip_runtime.h>
#include <math.h>

// MemoryCenters: sim = q·K^T (1024x100000, D=128), top-32 by rbf=exp(-2*dist_sq),
// softmax(log(rbf+eps)+log(h+eps)), r_V = w·V_sel, r_E = w·e_sel.
//
// Round 10 = Round 9 with the GEMM's occupancy PINNED: amdgpu_waves_per_eu(4,4).
// R8/R9 evidence: __launch_bounds__(512,4) only sets MIN waves/EU; the allocator
// heuristic still aimed for 8 waves/EU -> 64-VGPR budget -> spilled the A-frags
// (R9: 24.8MB scratch writes, 8MB scratch reads). LDS (66KB) caps at 2 blocks/CU
// = 4 waves/EU anyway, so pinning (4,4) costs nothing and restores the 128-VGPR
// budget (af 32 + acc 32 + bg 16 + thrv/addr ~= 110 < 128, no spill).
// convert/thresh/finalize identical to passing R9.
// ws: 25.6MB Kbf + 256KB Qbf + 4KB thr + 256KB cnt2 + 12.58MB (binsU8|buckets).

#define DDIM    128
#define MSAMPLE 12288
#define NBINS   256
#define TOPK    32
#define NQTOT   1024
#define NGRP    64
#define BCAP    48
#define EPSM    0.012f
#define SORTN   1024
#define FINEN   256
#define QSH     17
#define QMASK   0x1FFFFu
#define QMARGIN 200u      // 200/16384 = 0.0122 >= 2*EA(0.004) + 2 quanta

typedef __attribute__((ext_vector_type(8))) short short8;   // 8 bf16 = 4 VGPRs
typedef __attribute__((ext_vector_type(4))) float f32x4;    // mfma C/D frag

__device__ inline unsigned short f2bf(float f) {
    unsigned u = __builtin_bit_cast(unsigned, f);
    return (unsigned short)((u + 0x7FFFu + ((u >> 16) & 1u)) >> 16);
}

// ---------------------------------------------------------------------------
__global__ __launch_bounds__(256)
void convert_kernel(const float* __restrict__ Qg, const float* __restrict__ Kg,
                    unsigned short* __restrict__ Qbf, unsigned short* __restrict__ Kbf,
                    int nq8, int nk8)
{
    int total = nq8 + nk8;
    for (int i = blockIdx.x * 256 + threadIdx.x; i < total; i += gridDim.x * 256) {
        const float* s; unsigned short* d; int j;
        if (i < nq8) { s = Qg; d = Qbf; j = i; }
        else         { s = Kg; d = Kbf; j = i - nq8; }
        float4 a = *reinterpret_cast<const float4*>(s + (size_t)j * 8);
        float4 b = *reinterpret_cast<const float4*>(s + (size_t)j * 8 + 4);
        short8 o;
        o[0] = (short)f2bf(a.x); o[1] = (short)f2bf(a.y);
        o[2] = (short)f2bf(a.z); o[3] = (short)f2bf(a.w);
        o[4] = (short)f2bf(b.x); o[5] = (short)f2bf(b.y);
        o[6] = (short)f2bf(b.z); o[7] = (short)f2bf(b.w);
        *reinterpret_cast<short8*>(d + (size_t)j * 8) = o;
    }
}

// ---------------------------------------------------------------------------
// bf16 MFMA GEMM, 128x128 tile, 8 waves (4 row x 2 col; wave = 32q x 64c),
// A in registers (af[2][4]), B double-buffered via global_load_lds
// (pre-swizzled source cc^(r&15), linear LDS dest, swizzled read).
// Occupancy pinned at exactly 4 waves/EU (matches the 2-blocks/CU LDS cap)
// so the allocator keeps the full 128-VGPR budget and does NOT spill.
// MODE 0: u8 bins. MODE 1: bucket-append packed keys.
// ---------------------------------------------------------------------------
template<int MODE>
__global__ __launch_bounds__(512)
__attribute__((amdgpu_waves_per_eu(4, 4)))
void gemm_pass(const unsigned short* __restrict__ Qb, const unsigned short* __restrict__ Kb,
               int N, unsigned char* __restrict__ binsU8,
               const float* __restrict__ thr,
               int* __restrict__ cnt2, unsigned int* __restrict__ buckets)
{
    __shared__ __align__(16) unsigned char Bs[2][128 * 256];  // 2 x 32KB
    __shared__ int off_l[128];
    const int tid   = threadIdx.x;
    const int lane  = tid & 63;
    const int w     = tid >> 6;           // 0..7
    const int wr    = (w >> 1) * 32;      // 4 row blocks of 32 q
    const int wc    = (w & 1) * 64;       // 2 col blocks of 64 c
    const int lr    = lane & 15;
    const int lk    = lane >> 4;          // 0..3
    const int g     = blockIdx.x;
    const int qbase = blockIdx.y * 128;

    int t0, tcnt;
    if (MODE == 0) { t0 = g; tcnt = 1; }
    else { t0 = g * 12 + min(g, 14); tcnt = 12 + (g < 14 ? 1 : 0); }  // 782 tiles

    if (MODE == 1)
        for (int i = tid; i < 128; i += 512) off_l[i] = 0;

#define STAGE(buf, tile) do {                                                  \
    const int cbase_ = (tile) * 128;                                           \
    _Pragma("unroll")                                                          \
    for (int it = 0; it < 4; ++it) {                                           \
        int flat = it * 512 + tid;                                             \
        int r_ = flat >> 4, cc_ = flat & 15;                                   \
        int row_ = cbase_ + r_;                                                \
        if (MODE == 1 && row_ >= N) row_ = N - 1;  /* epilogue c<N discards */ \
        const unsigned short* src_ = Kb + (size_t)row_ * DDIM                  \
                                        + ((cc_ ^ (r_ & 15)) * 8);             \
        unsigned char* dst_ = &Bs[buf][(size_t)(it * 512 + (tid & ~63)) * 16]; \
        __builtin_amdgcn_global_load_lds(                                      \
            (const __attribute__((address_space(1))) unsigned int*)src_,       \
            (__attribute__((address_space(3))) unsigned int*)dst_, 16, 0, 0);  \
    }                                                                          \
} while (0)

    // ---- A fragments in registers: af[fm][ks] = 8 short8 = 32 VGPR ----
    short8 af[2][4];
    #pragma unroll
    for (int fm = 0; fm < 2; ++fm)
        #pragma unroll
        for (int ks = 0; ks < 4; ++ks)
            af[fm][ks] = *reinterpret_cast<const short8*>(
                Qb + (size_t)(qbase + wr + fm * 16 + lr) * DDIM + (ks * 4 + lk) * 8);

    float thrv[2][4];
    if (MODE == 1) {
        #pragma unroll
        for (int fm = 0; fm < 2; ++fm)
            #pragma unroll
            for (int j = 0; j < 4; ++j)
                thrv[fm][j] = thr[qbase + wr + fm * 16 + lk * 4 + j] - EPSM;
    }

    STAGE(0, t0);
    __syncthreads();
    int cur = 0;

    for (int t = 0; t < tcnt; ++t) {
        if (t + 1 < tcnt) STAGE(cur ^ 1, t0 + t + 1);   // in flight under compute

        const int cbase = (t0 + t) * 128;
        const unsigned char* bsc = Bs[cur];

        const f32x4 z = {0.f, 0.f, 0.f, 0.f};
        f32x4 acc[2][4];
        #pragma unroll
        for (int a = 0; a < 2; ++a)
            #pragma unroll
            for (int b = 0; b < 4; ++b) acc[a][b] = z;

        #pragma unroll
        for (int ks = 0; ks < 4; ++ks) {
            short8 bg[4];
            #pragma unroll
            for (int fn = 0; fn < 4; ++fn) {
                int rb = wc + fn * 16 + lr;
                bg[fn] = *reinterpret_cast<const short8*>(
                    bsc + rb * 256 + (((ks * 4 + lk) ^ (rb & 15)) << 4));
            }
            #pragma unroll
            for (int fm = 0; fm < 2; ++fm)
                #pragma unroll
                for (int fn = 0; fn < 4; ++fn)
                    acc[fm][fn] = __builtin_amdgcn_mfma_f32_16x16x32_bf16(
                        af[fm][ks], bg[fn], acc[fm][fn], 0, 0, 0);
        }

        // epilogue — C/D map: col = lane&15, row = (lane>>4)*4 + reg [m89/m91]
        #pragma unroll
        for (int fm = 0; fm < 2; ++fm) {
            #pragma unroll
            for (int j = 0; j < 4; ++j) {
                const int ql = wr + fm * 16 + lk * 4 + j;
                if (MODE == 0) {
                    #pragma unroll
                    for (int fn = 0; fn < 4; ++fn) {
                        const int c = cbase + wc + fn * 16 + lr;
                        float s = acc[fm][fn][j];
                        int b = (int)((s + 1.0f) * (NBINS * 0.5f));
                        b = b < 0 ? 0 : (b > NBINS - 1 ? NBINS - 1 : b);
                        binsU8[(size_t)(qbase + ql) * MSAMPLE + c] = (unsigned char)b;
                    }
                } else {
                    const float t_ = thrv[fm][j];
                    const float m01 = fmaxf(acc[fm][0][j], acc[fm][1][j]);
                    const float m23 = fmaxf(acc[fm][2][j], acc[fm][3][j]);
                    if (__any(fmaxf(m01, m23) >= t_)) {
                        #pragma unroll
                        for (int fn = 0; fn < 4; ++fn) {
                            const int c = cbase + wc + fn * 16 + lr;
                            const float s = acc[fm][fn][j];
                            if (c < N && s >= t_) {
                                int qs = (int)((s + 1.0f) * 16384.0f);
                                qs = qs < 0 ? 0 : (qs > 32767 ? 32767 : qs);
                                unsigned key = ((unsigned)qs << QSH)
                                             | (~(unsigned)c & QMASK);
                                int p = atomicAdd(&off_l[ql], 1);   // LDS-local
                                if (p < BCAP)
                                    buckets[((size_t)(qbase + ql) * NGRP + g) * BCAP + p] = key;
                            }
                        }
                    }
                }
            }
        }
        __syncthreads();
        cur ^= 1;
    }
#undef STAGE

    if (MODE == 1) {
        for (int i = tid; i < 128; i += 512)
            cnt2[(qbase + i) * NGRP + g] = min(off_l[i], BCAP);
    }
}

// ---------------------------------------------------------------------------
// thresh with per-wave sub-histograms
// ---------------------------------------------------------------------------
__global__ __launch_bounds__(256)
void thresh_kernel(const unsigned char* __restrict__ bins, float* __restrict__ thr)
{
    __shared__ int hS[4 * NBINS];
    __shared__ int hA[NBINS];
    __shared__ int hB[NBINS];
    __shared__ int best;
    const int q = blockIdx.x, tid = threadIdx.x;
    const int wv = tid >> 6;
    for (int i = tid; i < 4 * NBINS; i += 256) hS[i] = 0;
    if (tid == 0) best = 0;
    __syncthreads();
    const uint4* bp = reinterpret_cast<const uint4*>(bins + (size_t)q * MSAMPLE);
    int* hw = hS + wv * NBINS;
    for (int i = tid; i < MSAMPLE / 16; i += 256) {
        uint4 v = bp[i];
        unsigned xs[4] = {v.x, v.y, v.z, v.w};
        #pragma unroll
        for (int k = 0; k < 4; ++k) {
            unsigned x = xs[k];
            atomicAdd(&hw[x & 255], 1); x >>= 8;
            atomicAdd(&hw[x & 255], 1); x >>= 8;
            atomicAdd(&hw[x & 255], 1); x >>= 8;
            atomicAdd(&hw[x & 255], 1);
        }
    }
    __syncthreads();
    for (int i = tid; i < NBINS; i += 256)
        hA[i] = hS[i] + hS[NBINS + i] + hS[2 * NBINS + i] + hS[3 * NBINS + i];
    __syncthreads();
    int* src = hA; int* dst = hB;
    for (int off = 1; off < NBINS; off <<= 1) {
        for (int i = tid; i < NBINS; i += 256)
            dst[i] = src[i] + ((i + off < NBINS) ? src[i + off] : 0);
        __syncthreads();
        int* tmp = src; src = dst; dst = tmp;
    }
    for (int i = tid; i < NBINS; i += 256)
        if (src[i] >= TOPK) atomicMax(&best, i);
    __syncthreads();
    if (tid == 0)
        thr[q] = (float)(best - 1) * (2.0f / NBINS) - 1.0f;
}

// ---------------------------------------------------------------------------
// Finalize: compact packed keys -> 1024-wide u32 bitonic (approx desc) ->
// exact fp32 rbf ONLY for head slots within QMARGIN of 32nd approx key ->
// 256-wide u64 bitonic (rbf desc, idx asc = jax.lax.top_k) -> weights, gathers.
// ---------------------------------------------------------------------------
__global__ __launch_bounds__(256)
void finalize_kernel(const unsigned int* __restrict__ buckets, const int* __restrict__ cnt2,
                     const float* __restrict__ Qg, const float* __restrict__ Kg,
                     const float* __restrict__ V, const float* __restrict__ hIn,
                     const float* __restrict__ eIn,
                     float* __restrict__ out, int N)
{
    __shared__ float qv[DDIM];
    __shared__ unsigned sk[SORTN];                 // 4KB packed approx keys
    __shared__ unsigned long long sk64[FINEN];     // 2KB exact keys
    __shared__ int cnts[NGRP], offs[NGRP];
    __shared__ int ntot;
    __shared__ float selV[TOPK];
    __shared__ int   selI[TOPK];
    __shared__ float wts[TOPK];
    const int q = blockIdx.x, tid = threadIdx.x;

    if (tid < DDIM) qv[tid] = Qg[(size_t)q * DDIM + tid];
    if (tid < NGRP) cnts[tid] = cnt2[q * NGRP + tid];
    for (int i = tid; i < SORTN; i += 256) sk[i] = 0u;     // pad sorts last
    if (tid < FINEN) sk64[tid] = 0ull;
    __syncthreads();
    if (tid < NGRP) {
        int c = cnts[tid];
        int x = c;
        #pragma unroll
        for (int o = 1; o < NGRP; o <<= 1) {
            int y = __shfl_up(x, o);
            if (tid >= o) x += y;
        }
        offs[tid] = x - c;
        if (tid == NGRP - 1) ntot = x;
    }
    __syncthreads();
    for (int flat = tid; flat < NGRP * BCAP; flat += 256) {
        int gg = flat / BCAP, j = flat - gg * BCAP;
        if (j < cnts[gg]) {
            int dst = offs[gg] + j;
            if (dst < SORTN)
                sk[dst] = buckets[((size_t)q * NGRP + gg) * BCAP + j];
        }
    }
    __syncthreads();
    // bitonic sort u32 desc, 1024 elems, 256 threads
    for (int k = 2; k <= SORTN; k <<= 1) {
        for (int j = k >> 1; j > 0; j >>= 1) {
            for (int t = tid; t < SORTN; t += 256) {
                int x = t ^ j;
                if (x > t) {
                    unsigned a = sk[t], b = sk[x];
                    bool sw = ((t & k) == 0) ? (a < b) : (a > b);
                    if (sw) { sk[t] = b; sk[x] = a; }
                }
            }
            __syncthreads();
        }
    }
    // exact recompute for head slots within QMARGIN of the 32nd approx key
    const unsigned a32q = sk[TOPK - 1] >> QSH;
    const unsigned cutq = a32q > QMARGIN ? a32q - QMARGIN : 0u;
    const int sub = tid & 3, ci = tid >> 2;
    #pragma unroll
    for (int base = 0; base < FINEN; base += 64) {
        int i = base + ci;
        unsigned key = sk[i];
        bool act = (key != 0u) && ((key >> QSH) >= cutq);
        int c = (int)(~key & QMASK);
        float s = 0.f;
        if (act) {
            const float4* k4 = reinterpret_cast<const float4*>(Kg + (size_t)c * DDIM) + sub;
            const float4* q4 = reinterpret_cast<const float4*>(qv) + sub;
            #pragma unroll
            for (int d = 0; d < 8; ++d) {
                float4 kk = k4[d * 4];
                float4 qq = q4[d * 4];
                s = fmaf(qq.x, kk.x, s); s = fmaf(qq.y, kk.y, s);
                s = fmaf(qq.z, kk.z, s); s = fmaf(qq.w, kk.w, s);
            }
        }
        s += __shfl_xor(s, 1); s += __shfl_xor(s, 2);
        if (act && sub == 0) {
            float dist = 2.0f - 2.0f * s;              // reference op order
            float rbf = expf(dist * -2.0f);            // exp(-dist/(2*0.25))
            sk64[i] = ((unsigned long long)__float_as_uint(rbf) << 32)
                    | (unsigned)(~(unsigned)c);        // rbf desc, then idx asc
        }
    }
    __syncthreads();
    // bitonic sort u64 desc, 256 elems, 256 threads (1 CE owner per pair)
    for (int k = 2; k <= FINEN; k <<= 1) {
        for (int j = k >> 1; j > 0; j >>= 1) {
            int x = tid ^ j;
            if (x > tid) {
                unsigned long long a = sk64[tid], b = sk64[x];
                bool sw = ((tid & k) == 0) ? (a < b) : (a > b);
                if (sw) { sk64[tid] = b; sk64[x] = a; }
            }
            __syncthreads();
        }
    }
    if (tid < TOPK) {
        unsigned long long kk = sk64[tid];
        float rbf = __uint_as_float((unsigned)(kk >> 32));
        int   idx = (int)(~(unsigned)kk);
        selV[tid] = rbf; selI[tid] = idx;
        float lw = logf(rbf + 1e-8f) + logf(hIn[idx] + 1e-8f);
        float mx = lw;
        #pragma unroll
        for (int o = 16; o > 0; o >>= 1) mx = fmaxf(mx, __shfl_xor(mx, o));
        float ex = expf(lw - mx);
        float sm = ex;
        #pragma unroll
        for (int o = 16; o > 0; o >>= 1) sm += __shfl_xor(sm, o);
        wts[tid] = ex / sm;
    }
    __syncthreads();
    {
        float acc = 0.f;
        const int v = tid;
        #pragma unroll
        for (int k = 0; k < TOPK; ++k)
            acc = fmaf(wts[k], V[(size_t)selI[k] * 256 + v], acc);
        out[(size_t)q * 256 + v] = acc;
    }
    const int offE = NQTOT * 256;
    const int offW = offE + NQTOT * 4;
    const int offI = offW + NQTOT * TOPK;
    if (tid < 4) {
        float acc = 0.f;
        #pragma unroll
        for (int k = 0; k < TOPK; ++k)
            acc = fmaf(wts[k], eIn[(size_t)selI[k] * 4 + tid], acc);
        out[offE + q * 4 + tid] = acc;
    }
    if (tid < TOPK) {
        out[offW + q * TOPK + tid] = wts[tid];
        out[offI + q * TOPK + tid] = (float)selI[tid];
    }
}

// ---------------------------------------------------------------------------
extern "C" void kernel_launch(void* const* d_in, const int* in_sizes, int n_in,
                              void* d_out, int out_size, void* d_ws, size_t ws_size,
                              hipStream_t stream)
{
    (void)n_in; (void)out_size; (void)ws_size;
    const float* Qg = (const float*)d_in[0];
    const float* Kg = (const float*)d_in[1];
    const float* Vg = (const float*)d_in[2];
    const float* hg = (const float*)d_in[3];
    const float* eg = (const float*)d_in[4];
    const int N = in_sizes[1] / DDIM;          // 100000

    char* w = (char*)d_ws;
    unsigned short* Kbf = (unsigned short*)w;  w += (size_t)N * DDIM * 2;      // 25.6MB
    unsigned short* Qbf = (unsigned short*)w;  w += (size_t)NQTOT * DDIM * 2;  // 256KB
    float* thr = (float*)w;                    w += NQTOT * 4;                 // 4KB
    int*   cnt2 = (int*)w;                     w += (size_t)NQTOT * NGRP * 4;  // 256KB
    unsigned char* binsU8 = (unsigned char*)w;                                 // 12.58MB
    unsigned int*  buckets = (unsigned int*)w; // aliases binsU8 (sequential lifetimes)

    hipMemsetAsync(cnt2, 0, (size_t)NQTOT * NGRP * 4, stream);

    dim3 blk(256);
    dim3 blk512(512);
    convert_kernel<<<dim3(2048), blk, 0, stream>>>(
        Qg, Kg, Qbf, Kbf, NQTOT * DDIM / 8, N * DDIM / 8);
    gemm_pass<0><<<dim3(MSAMPLE / 128, NQTOT / 128), blk512, 0, stream>>>(
        Qbf, Kbf, N, binsU8, nullptr, nullptr, nullptr);
    thresh_kernel<<<dim3(NQTOT), blk, 0, stream>>>(binsU8, thr);
    gemm_pass<1><<<dim3(NGRP, NQTOT / 128), blk512, 0, stream>>>(
        Qbf, Kbf, N, nullptr, thr, cnt2, buckets);
    finalize_kernel<<<dim3(NQTOT), blk, 0, stream>>>(
        buckets, cnt2, Qg, Kg, Vg, hg, eg, (float*)d_out, N);
}

// Round 11
// 158.769 us; speedup vs baseline: 1.0462x; 1.0462x over previous
//
#include <hip/hip_runtime.h>
#include <math.h>

// MemoryCenters: sim = q·K^T (1024x100000, D=128), top-32 by rbf=exp(-2*dist_sq),
// softmax(log(rbf+eps)+log(h+eps)), r_V = w·V_sel, r_E = w·e_sel.
//
// Round 11: R8-R10 proved 512-thread blocks get VGPR pinned to 64 by the
// allocator (spill: 24.7MB scratch writes) no matter what launch_bounds /
// waves_per_eu says. 256-thread blocks provably get 100-124 VGPR (R5-R7).
// So: 16 waves/CU via FOUR 256-thread blocks/CU instead of two 512s:
//   - tile 64q x 64c, 4 waves of 32q x 32c (af[2][4]=32 + acc[2][2]=16 +
//     bg[2]=8 + thrv=8 ~= 80 VGPR -> no spill pressure)
//   - B dbuf 2x16KB -> 33KB LDS -> 4 blocks/CU = 16 waves/CU
//   - grid (128 groups x 16 qtiles) = 2048 blocks
//   - same cc^(r&15) swizzle, global_load_lds, 2-phase pipeline, k-order
//     -> bitwise-identical sims -> identical survivor set.
// NGRP 64->128, BCAP 48->24 (lambda~5.3/bucket; buckets=12.58MB aliases binsU8).
// finalize: 128-group prefix scan (2-wave hierarchical). ws ~= 39.0MB.

#define DDIM    128
#define MSAMPLE 12288
#define NBINS   256
#define TOPK    32
#define NQTOT   1024
#define NGRP    128
#define BCAP    24
#define EPSM    0.012f
#define SORTN   1024
#define FINEN   256
#define QSH     17
#define QMASK   0x1FFFFu
#define QMARGIN 200u      // 200/16384 = 0.0122 >= 2*EA(0.004) + 2 quanta

typedef __attribute__((ext_vector_type(8))) short short8;   // 8 bf16 = 4 VGPRs
typedef __attribute__((ext_vector_type(4))) float f32x4;    // mfma C/D frag

__device__ inline unsigned short f2bf(float f) {
    unsigned u = __builtin_bit_cast(unsigned, f);
    return (unsigned short)((u + 0x7FFFu + ((u >> 16) & 1u)) >> 16);
}

// ---------------------------------------------------------------------------
__global__ __launch_bounds__(256)
void convert_kernel(const float* __restrict__ Qg, const float* __restrict__ Kg,
                    unsigned short* __restrict__ Qbf, unsigned short* __restrict__ Kbf,
                    int nq8, int nk8)
{
    int total = nq8 + nk8;
    for (int i = blockIdx.x * 256 + threadIdx.x; i < total; i += gridDim.x * 256) {
        const float* s; unsigned short* d; int j;
        if (i < nq8) { s = Qg; d = Qbf; j = i; }
        else         { s = Kg; d = Kbf; j = i - nq8; }
        float4 a = *reinterpret_cast<const float4*>(s + (size_t)j * 8);
        float4 b = *reinterpret_cast<const float4*>(s + (size_t)j * 8 + 4);
        short8 o;
        o[0] = (short)f2bf(a.x); o[1] = (short)f2bf(a.y);
        o[2] = (short)f2bf(a.z); o[3] = (short)f2bf(a.w);
        o[4] = (short)f2bf(b.x); o[5] = (short)f2bf(b.y);
        o[6] = (short)f2bf(b.z); o[7] = (short)f2bf(b.w);
        *reinterpret_cast<short8*>(d + (size_t)j * 8) = o;
    }
}

// ---------------------------------------------------------------------------
// bf16 MFMA GEMM, 64x64 tile, 4 waves (2 row x 2 col; wave = 32q x 32c),
// A in registers (af[2][4]), B double-buffered (2x16KB) via global_load_lds
// (pre-swizzled source cc^(r&15), linear LDS dest, swizzled read).
// 33KB LDS -> 4 blocks/CU = 16 waves/CU at 256 threads (no VGPR pinning).
// MODE 0: u8 bins. MODE 1: bucket-append packed keys.
// ---------------------------------------------------------------------------
template<int MODE>
__global__ __launch_bounds__(256)
void gemm_pass(const unsigned short* __restrict__ Qb, const unsigned short* __restrict__ Kb,
               int N, unsigned char* __restrict__ binsU8,
               const float* __restrict__ thr,
               int* __restrict__ cnt2, unsigned int* __restrict__ buckets)
{
    __shared__ __align__(16) unsigned char Bs[2][64 * 256];  // 2 x 16KB
    __shared__ int off_l[64];
    const int tid   = threadIdx.x;
    const int lane  = tid & 63;
    const int w     = tid >> 6;           // 0..3
    const int wr    = (w >> 1) * 32;      // 2 row blocks of 32 q
    const int wc    = (w & 1) * 32;       // 2 col blocks of 32 c
    const int lr    = lane & 15;
    const int lk    = lane >> 4;          // 0..3
    const int g     = blockIdx.x;
    const int qbase = blockIdx.y * 64;

    int t0, tcnt;
    if (MODE == 0) { t0 = g; tcnt = 1; }                      // 192 sample tiles
    else { t0 = g * 12 + min(g, 27); tcnt = 12 + (g < 27 ? 1 : 0); }  // 1563 tiles

    if (MODE == 1)
        for (int i = tid; i < 64; i += 256) off_l[i] = 0;

#define STAGE(buf, tile) do {                                                  \
    const int cbase_ = (tile) * 64;                                            \
    _Pragma("unroll")                                                          \
    for (int it = 0; it < 4; ++it) {                                           \
        int flat = it * 256 + tid;                                             \
        int r_ = flat >> 4, cc_ = flat & 15;                                   \
        int row_ = cbase_ + r_;                                                \
        if (MODE == 1 && row_ >= N) row_ = N - 1;  /* epilogue c<N discards */ \
        const unsigned short* src_ = Kb + (size_t)row_ * DDIM                  \
                                        + ((cc_ ^ (r_ & 15)) * 8);             \
        unsigned char* dst_ = &Bs[buf][(size_t)(it * 256 + (tid & ~63)) * 16]; \
        __builtin_amdgcn_global_load_lds(                                      \
            (const __attribute__((address_space(1))) unsigned int*)src_,       \
            (__attribute__((address_space(3))) unsigned int*)dst_, 16, 0, 0);  \
    }                                                                          \
} while (0)

    // ---- A fragments in registers: af[fm][ks] = 8 short8 = 32 VGPR ----
    short8 af[2][4];
    #pragma unroll
    for (int fm = 0; fm < 2; ++fm)
        #pragma unroll
        for (int ks = 0; ks < 4; ++ks)
            af[fm][ks] = *reinterpret_cast<const short8*>(
                Qb + (size_t)(qbase + wr + fm * 16 + lr) * DDIM + (ks * 4 + lk) * 8);

    float thrv[2][4];
    if (MODE == 1) {
        #pragma unroll
        for (int fm = 0; fm < 2; ++fm)
            #pragma unroll
            for (int j = 0; j < 4; ++j)
                thrv[fm][j] = thr[qbase + wr + fm * 16 + lk * 4 + j] - EPSM;
    }

    STAGE(0, t0);
    __syncthreads();
    int cur = 0;

    for (int t = 0; t < tcnt; ++t) {
        if (t + 1 < tcnt) STAGE(cur ^ 1, t0 + t + 1);   // in flight under compute

        const int cbase = (t0 + t) * 64;
        const unsigned char* bsc = Bs[cur];

        const f32x4 z = {0.f, 0.f, 0.f, 0.f};
        f32x4 acc[2][2];
        #pragma unroll
        for (int a = 0; a < 2; ++a)
            #pragma unroll
            for (int b = 0; b < 2; ++b) acc[a][b] = z;

        #pragma unroll
        for (int ks = 0; ks < 4; ++ks) {
            short8 bg[2];
            #pragma unroll
            for (int fn = 0; fn < 2; ++fn) {
                int rb = wc + fn * 16 + lr;
                bg[fn] = *reinterpret_cast<const short8*>(
                    bsc + rb * 256 + (((ks * 4 + lk) ^ (rb & 15)) << 4));
            }
            #pragma unroll
            for (int fm = 0; fm < 2; ++fm)
                #pragma unroll
                for (int fn = 0; fn < 2; ++fn)
                    acc[fm][fn] = __builtin_amdgcn_mfma_f32_16x16x32_bf16(
                        af[fm][ks], bg[fn], acc[fm][fn], 0, 0, 0);
        }

        // epilogue — C/D map: col = lane&15, row = (lane>>4)*4 + reg [m89/m91]
        #pragma unroll
        for (int fm = 0; fm < 2; ++fm) {
            #pragma unroll
            for (int j = 0; j < 4; ++j) {
                const int ql = wr + fm * 16 + lk * 4 + j;
                if (MODE == 0) {
                    #pragma unroll
                    for (int fn = 0; fn < 2; ++fn) {
                        const int c = cbase + wc + fn * 16 + lr;
                        float s = acc[fm][fn][j];
                        int b = (int)((s + 1.0f) * (NBINS * 0.5f));
                        b = b < 0 ? 0 : (b > NBINS - 1 ? NBINS - 1 : b);
                        binsU8[(size_t)(qbase + ql) * MSAMPLE + c] = (unsigned char)b;
                    }
                } else {
                    const float t_ = thrv[fm][j];
                    const float s0 = acc[fm][0][j], s1 = acc[fm][1][j];
                    if (__any(fmaxf(s0, s1) >= t_)) {
                        #pragma unroll
                        for (int fn = 0; fn < 2; ++fn) {
                            const int c = cbase + wc + fn * 16 + lr;
                            const float s = fn ? s1 : s0;
                            if (c < N && s >= t_) {
                                int qs = (int)((s + 1.0f) * 16384.0f);
                                qs = qs < 0 ? 0 : (qs > 32767 ? 32767 : qs);
                                unsigned key = ((unsigned)qs << QSH)
                                             | (~(unsigned)c & QMASK);
                                int p = atomicAdd(&off_l[ql], 1);   // LDS-local
                                if (p < BCAP)
                                    buckets[((size_t)(qbase + ql) * NGRP + g) * BCAP + p] = key;
                            }
                        }
                    }
                }
            }
        }
        __syncthreads();
        cur ^= 1;
    }
#undef STAGE

    if (MODE == 1) {
        for (int i = tid; i < 64; i += 256)
            cnt2[(qbase + i) * NGRP + g] = min(off_l[i], BCAP);
    }
}

// ---------------------------------------------------------------------------
// thresh with per-wave sub-histograms
// ---------------------------------------------------------------------------
__global__ __launch_bounds__(256)
void thresh_kernel(const unsigned char* __restrict__ bins, float* __restrict__ thr)
{
    __shared__ int hS[4 * NBINS];
    __shared__ int hA[NBINS];
    __shared__ int hB[NBINS];
    __shared__ int best;
    const int q = blockIdx.x, tid = threadIdx.x;
    const int wv = tid >> 6;
    for (int i = tid; i < 4 * NBINS; i += 256) hS[i] = 0;
    if (tid == 0) best = 0;
    __syncthreads();
    const uint4* bp = reinterpret_cast<const uint4*>(bins + (size_t)q * MSAMPLE);
    int* hw = hS + wv * NBINS;
    for (int i = tid; i < MSAMPLE / 16; i += 256) {
        uint4 v = bp[i];
        unsigned xs[4] = {v.x, v.y, v.z, v.w};
        #pragma unroll
        for (int k = 0; k < 4; ++k) {
            unsigned x = xs[k];
            atomicAdd(&hw[x & 255], 1); x >>= 8;
            atomicAdd(&hw[x & 255], 1); x >>= 8;
            atomicAdd(&hw[x & 255], 1); x >>= 8;
            atomicAdd(&hw[x & 255], 1);
        }
    }
    __syncthreads();
    for (int i = tid; i < NBINS; i += 256)
        hA[i] = hS[i] + hS[NBINS + i] + hS[2 * NBINS + i] + hS[3 * NBINS + i];
    __syncthreads();
    int* src = hA; int* dst = hB;
    for (int off = 1; off < NBINS; off <<= 1) {
        for (int i = tid; i < NBINS; i += 256)
            dst[i] = src[i] + ((i + off < NBINS) ? src[i + off] : 0);
        __syncthreads();
        int* tmp = src; src = dst; dst = tmp;
    }
    for (int i = tid; i < NBINS; i += 256)
        if (src[i] >= TOPK) atomicMax(&best, i);
    __syncthreads();
    if (tid == 0)
        thr[q] = (float)(best - 1) * (2.0f / NBINS) - 1.0f;
}

// ---------------------------------------------------------------------------
// Finalize: compact packed keys (128 groups, 2-wave hierarchical scan) ->
// 1024-wide u32 bitonic (approx desc) -> exact fp32 rbf ONLY for head slots
// within QMARGIN of 32nd approx key -> 256-wide u64 bitonic (rbf desc, idx asc
// = jax.lax.top_k) -> weights, V/e gathers.
// ---------------------------------------------------------------------------
__global__ __launch_bounds__(256)
void finalize_kernel(const unsigned int* __restrict__ buckets, const int* __restrict__ cnt2,
                     const float* __restrict__ Qg, const float* __restrict__ Kg,
                     const float* __restrict__ V, const float* __restrict__ hIn,
                     const float* __restrict__ eIn,
                     float* __restrict__ out, int N)
{
    __shared__ float qv[DDIM];
    __shared__ unsigned sk[SORTN];                 // 4KB packed approx keys
    __shared__ unsigned long long sk64[FINEN];     // 2KB exact keys
    __shared__ int cnts[NGRP], offs[NGRP];
    __shared__ int wpart[2];
    __shared__ int ntot;
    __shared__ float selV[TOPK];
    __shared__ int   selI[TOPK];
    __shared__ float wts[TOPK];
    const int q = blockIdx.x, tid = threadIdx.x;

    if (tid < DDIM) qv[tid] = Qg[(size_t)q * DDIM + tid];
    if (tid < NGRP) cnts[tid] = cnt2[q * NGRP + tid];
    for (int i = tid; i < SORTN; i += 256) sk[i] = 0u;     // pad sorts last
    if (tid < FINEN) sk64[tid] = 0ull;
    __syncthreads();
    // 128-wide inclusive scan: per-wave shfl scan + wave-1 offset
    int cv = 0, xv = 0;
    if (tid < NGRP) {
        cv = cnts[tid];
        xv = cv;
        #pragma unroll
        for (int o = 1; o < 64; o <<= 1) {
            int y = __shfl_up(xv, o);
            if ((tid & 63) >= o) xv += y;
        }
        if ((tid & 63) == 63) wpart[tid >> 6] = xv;
    }
    __syncthreads();
    if (tid < NGRP) {
        int add = (tid >= 64) ? wpart[0] : 0;
        offs[tid] = xv - cv + add;
        if (tid == NGRP - 1) ntot = xv + add;
    }
    __syncthreads();
    for (int flat = tid; flat < NGRP * BCAP; flat += 256) {
        int gg = flat / BCAP, j = flat - gg * BCAP;
        if (j < cnts[gg]) {
            int dst = offs[gg] + j;
            if (dst < SORTN)
                sk[dst] = buckets[((size_t)q * NGRP + gg) * BCAP + j];
        }
    }
    __syncthreads();
    // bitonic sort u32 desc, 1024 elems, 256 threads
    for (int k = 2; k <= SORTN; k <<= 1) {
        for (int j = k >> 1; j > 0; j >>= 1) {
            for (int t = tid; t < SORTN; t += 256) {
                int x = t ^ j;
                if (x > t) {
                    unsigned a = sk[t], b = sk[x];
                    bool sw = ((t & k) == 0) ? (a < b) : (a > b);
                    if (sw) { sk[t] = b; sk[x] = a; }
                }
            }
            __syncthreads();
        }
    }
    // exact recompute for head slots within QMARGIN of the 32nd approx key
    const unsigned a32q = sk[TOPK - 1] >> QSH;
    const unsigned cutq = a32q > QMARGIN ? a32q - QMARGIN : 0u;
    const int sub = tid & 3, ci = tid >> 2;
    #pragma unroll
    for (int base = 0; base < FINEN; base += 64) {
        int i = base + ci;
        unsigned key = sk[i];
        bool act = (key != 0u) && ((key >> QSH) >= cutq);
        int c = (int)(~key & QMASK);
        float s = 0.f;
        if (act) {
            const float4* k4 = reinterpret_cast<const float4*>(Kg + (size_t)c * DDIM) + sub;
            const float4* q4 = reinterpret_cast<const float4*>(qv) + sub;
            #pragma unroll
            for (int d = 0; d < 8; ++d) {
                float4 kk = k4[d * 4];
                float4 qq = q4[d * 4];
                s = fmaf(qq.x, kk.x, s); s = fmaf(qq.y, kk.y, s);
                s = fmaf(qq.z, kk.z, s); s = fmaf(qq.w, kk.w, s);
            }
        }
        s += __shfl_xor(s, 1); s += __shfl_xor(s, 2);
        if (act && sub == 0) {
            float dist = 2.0f - 2.0f * s;              // reference op order
            float rbf = expf(dist * -2.0f);            // exp(-dist/(2*0.25))
            sk64[i] = ((unsigned long long)__float_as_uint(rbf) << 32)
                    | (unsigned)(~(unsigned)c);        // rbf desc, then idx asc
        }
    }
    __syncthreads();
    // bitonic sort u64 desc, 256 elems, 256 threads (1 CE owner per pair)
    for (int k = 2; k <= FINEN; k <<= 1) {
        for (int j = k >> 1; j > 0; j >>= 1) {
            int x = tid ^ j;
            if (x > tid) {
                unsigned long long a = sk64[tid], b = sk64[x];
                bool sw = ((tid & k) == 0) ? (a < b) : (a > b);
                if (sw) { sk64[tid] = b; sk64[x] = a; }
            }
            __syncthreads();
        }
    }
    if (tid < TOPK) {
        unsigned long long kk = sk64[tid];
        float rbf = __uint_as_float((unsigned)(kk >> 32));
        int   idx = (int)(~(unsigned)kk);
        selV[tid] = rbf; selI[tid] = idx;
        float lw = logf(rbf + 1e-8f) + logf(hIn[idx] + 1e-8f);
        float mx = lw;
        #pragma unroll
        for (int o = 16; o > 0; o >>= 1) mx = fmaxf(mx, __shfl_xor(mx, o));
        float ex = expf(lw - mx);
        float sm = ex;
        #pragma unroll
        for (int o = 16; o > 0; o >>= 1) sm += __shfl_xor(sm, o);
        wts[tid] = ex / sm;
    }
    __syncthreads();
    {
        float acc = 0.f;
        const int v = tid;
        #pragma unroll
        for (int k = 0; k < TOPK; ++k)
            acc = fmaf(wts[k], V[(size_t)selI[k] * 256 + v], acc);
        out[(size_t)q * 256 + v] = acc;
    }
    const int offE = NQTOT * 256;
    const int offW = offE + NQTOT * 4;
    const int offI = offW + NQTOT * TOPK;
    if (tid < 4) {
        float acc = 0.f;
        #pragma unroll
        for (int k = 0; k < TOPK; ++k)
            acc = fmaf(wts[k], eIn[(size_t)selI[k] * 4 + tid], acc);
        out[offE + q * 4 + tid] = acc;
    }
    if (tid < TOPK) {
        out[offW + q * TOPK + tid] = wts[tid];
        out[offI + q * TOPK + tid] = (float)selI[tid];
    }
}

// ---------------------------------------------------------------------------
extern "C" void kernel_launch(void* const* d_in, const int* in_sizes, int n_in,
                              void* d_out, int out_size, void* d_ws, size_t ws_size,
                              hipStream_t stream)
{
    (void)n_in; (void)out_size; (void)ws_size;
    const float* Qg = (const float*)d_in[0];
    const float* Kg = (const float*)d_in[1];
    const float* Vg = (const float*)d_in[2];
    const float* hg = (const float*)d_in[3];
    const float* eg = (const float*)d_in[4];
    const int N = in_sizes[1] / DDIM;          // 100000

    char* w = (char*)d_ws;
    unsigned short* Kbf = (unsigned short*)w;  w += (size_t)N * DDIM * 2;      // 25.6MB
    unsigned short* Qbf = (unsigned short*)w;  w += (size_t)NQTOT * DDIM * 2;  // 256KB
    float* thr = (float*)w;                    w += NQTOT * 4;                 // 4KB
    int*   cnt2 = (int*)w;                     w += (size_t)NQTOT * NGRP * 4;  // 512KB
    unsigned char* binsU8 = (unsigned char*)w;                                 // 12.58MB
    unsigned int*  buckets = (unsigned int*)w; // aliases binsU8 (sequential lifetimes)

    hipMemsetAsync(cnt2, 0, (size_t)NQTOT * NGRP * 4, stream);

    dim3 blk(256);
    convert_kernel<<<dim3(2048), blk, 0, stream>>>(
        Qg, Kg, Qbf, Kbf, NQTOT * DDIM / 8, N * DDIM / 8);
    gemm_pass<0><<<dim3(MSAMPLE / 64, NQTOT / 64), blk, 0, stream>>>(
        Qbf, Kbf, N, binsU8, nullptr, nullptr, nullptr);
    thresh_kernel<<<dim3(NQTOT), blk, 0, stream>>>(binsU8, thr);
    gemm_pass<1><<<dim3(NGRP, NQTOT / 64), blk, 0, stream>>>(
        Qbf, Kbf, N, nullptr, thr, cnt2, buckets);
    finalize_kernel<<<dim3(NQTOT), blk, 0, stream>>>(
        buckets, cnt2, Qg, Kg, Vg, hg, eg, (float*)d_out, N);
}

// Round 12
// 131.216 us; speedup vs baseline: 1.2659x; 1.2100x over previous
//
#include <hip/hip_runtime.h>
#include <math.h>

// MemoryCenters: sim = q·K^T (1024x100000, D=128), top-32 by rbf=exp(-2*dist_sq),
// softmax(log(rbf+eps)+log(h+eps)), r_V = w·V_sel, r_E = w·e_sel.
//
// Round 12 = Round 11 with finalize's 1024-wide u32 bitonic sort (55 barrier
// stages, the dominant serial cost: 70us, HBM-independent per warm replays)
// replaced by histogram RANK-SELECTION:
//   compact keys unsorted -> 256-bin histogram of key>>24 (qs>>7) -> suffix-sum
//   -> coarse bin b32 of the 32nd approx key -> cutq=(b32<<7)-QMARGIN (<= R11's
//   cut, so selection is a SUPERSET of the provably-complete R11 set; expected
//   ~110 <= 256 cap) -> LDS-append qualifiers -> exact fp32 recompute -> 256-wide
//   u64 bitonic on (rbf,~idx) unique keys (restores deterministic jax.lax.top_k
//   order regardless of append order) -> weights, V/e gathers.
// gemm/convert/thresh identical to passing R11.
// ws: 25.6MB Kbf + 256KB Qbf + 4KB thr + 512KB cnt2 + 12.58MB (binsU8|buckets).

#define DDIM    128
#define MSAMPLE 12288
#define NBINS   256
#define TOPK    32
#define NQTOT   1024
#define NGRP    128
#define BCAP    24
#define EPSM    0.012f
#define SORTN   1024
#define FINEN   256
#define QSH     17
#define QMASK   0x1FFFFu
#define QMARGIN 200u      // 200/16384 = 0.0122 >= 2*EA(0.004) + 2 quanta

typedef __attribute__((ext_vector_type(8))) short short8;   // 8 bf16 = 4 VGPRs
typedef __attribute__((ext_vector_type(4))) float f32x4;    // mfma C/D frag

__device__ inline unsigned short f2bf(float f) {
    unsigned u = __builtin_bit_cast(unsigned, f);
    return (unsigned short)((u + 0x7FFFu + ((u >> 16) & 1u)) >> 16);
}

// ---------------------------------------------------------------------------
__global__ __launch_bounds__(256)
void convert_kernel(const float* __restrict__ Qg, const float* __restrict__ Kg,
                    unsigned short* __restrict__ Qbf, unsigned short* __restrict__ Kbf,
                    int nq8, int nk8)
{
    int total = nq8 + nk8;
    for (int i = blockIdx.x * 256 + threadIdx.x; i < total; i += gridDim.x * 256) {
        const float* s; unsigned short* d; int j;
        if (i < nq8) { s = Qg; d = Qbf; j = i; }
        else         { s = Kg; d = Kbf; j = i - nq8; }
        float4 a = *reinterpret_cast<const float4*>(s + (size_t)j * 8);
        float4 b = *reinterpret_cast<const float4*>(s + (size_t)j * 8 + 4);
        short8 o;
        o[0] = (short)f2bf(a.x); o[1] = (short)f2bf(a.y);
        o[2] = (short)f2bf(a.z); o[3] = (short)f2bf(a.w);
        o[4] = (short)f2bf(b.x); o[5] = (short)f2bf(b.y);
        o[6] = (short)f2bf(b.z); o[7] = (short)f2bf(b.w);
        *reinterpret_cast<short8*>(d + (size_t)j * 8) = o;
    }
}

// ---------------------------------------------------------------------------
// bf16 MFMA GEMM, 64x64 tile, 4 waves (2x2; wave = 32q x 32c), A in registers,
// B double-buffered (2x16KB) via global_load_lds (pre-swizzled src cc^(r&15),
// linear LDS dest, swizzled read). 33KB LDS -> 4 blocks/CU = 16 waves/CU.
// MODE 0: u8 bins. MODE 1: bucket-append packed keys. (identical to R11)
// ---------------------------------------------------------------------------
template<int MODE>
__global__ __launch_bounds__(256)
void gemm_pass(const unsigned short* __restrict__ Qb, const unsigned short* __restrict__ Kb,
               int N, unsigned char* __restrict__ binsU8,
               const float* __restrict__ thr,
               int* __restrict__ cnt2, unsigned int* __restrict__ buckets)
{
    __shared__ __align__(16) unsigned char Bs[2][64 * 256];  // 2 x 16KB
    __shared__ int off_l[64];
    const int tid   = threadIdx.x;
    const int lane  = tid & 63;
    const int w     = tid >> 6;           // 0..3
    const int wr    = (w >> 1) * 32;
    const int wc    = (w & 1) * 32;
    const int lr    = lane & 15;
    const int lk    = lane >> 4;
    const int g     = blockIdx.x;
    const int qbase = blockIdx.y * 64;

    int t0, tcnt;
    if (MODE == 0) { t0 = g; tcnt = 1; }
    else { t0 = g * 12 + min(g, 27); tcnt = 12 + (g < 27 ? 1 : 0); }  // 1563 tiles

    if (MODE == 1)
        for (int i = tid; i < 64; i += 256) off_l[i] = 0;

#define STAGE(buf, tile) do {                                                  \
    const int cbase_ = (tile) * 64;                                            \
    _Pragma("unroll")                                                          \
    for (int it = 0; it < 4; ++it) {                                           \
        int flat = it * 256 + tid;                                             \
        int r_ = flat >> 4, cc_ = flat & 15;                                   \
        int row_ = cbase_ + r_;                                                \
        if (MODE == 1 && row_ >= N) row_ = N - 1;  /* epilogue c<N discards */ \
        const unsigned short* src_ = Kb + (size_t)row_ * DDIM                  \
                                        + ((cc_ ^ (r_ & 15)) * 8);             \
        unsigned char* dst_ = &Bs[buf][(size_t)(it * 256 + (tid & ~63)) * 16]; \
        __builtin_amdgcn_global_load_lds(                                      \
            (const __attribute__((address_space(1))) unsigned int*)src_,       \
            (__attribute__((address_space(3))) unsigned int*)dst_, 16, 0, 0);  \
    }                                                                          \
} while (0)

    short8 af[2][4];
    #pragma unroll
    for (int fm = 0; fm < 2; ++fm)
        #pragma unroll
        for (int ks = 0; ks < 4; ++ks)
            af[fm][ks] = *reinterpret_cast<const short8*>(
                Qb + (size_t)(qbase + wr + fm * 16 + lr) * DDIM + (ks * 4 + lk) * 8);

    float thrv[2][4];
    if (MODE == 1) {
        #pragma unroll
        for (int fm = 0; fm < 2; ++fm)
            #pragma unroll
            for (int j = 0; j < 4; ++j)
                thrv[fm][j] = thr[qbase + wr + fm * 16 + lk * 4 + j] - EPSM;
    }

    STAGE(0, t0);
    __syncthreads();
    int cur = 0;

    for (int t = 0; t < tcnt; ++t) {
        if (t + 1 < tcnt) STAGE(cur ^ 1, t0 + t + 1);

        const int cbase = (t0 + t) * 64;
        const unsigned char* bsc = Bs[cur];

        const f32x4 z = {0.f, 0.f, 0.f, 0.f};
        f32x4 acc[2][2];
        #pragma unroll
        for (int a = 0; a < 2; ++a)
            #pragma unroll
            for (int b = 0; b < 2; ++b) acc[a][b] = z;

        #pragma unroll
        for (int ks = 0; ks < 4; ++ks) {
            short8 bg[2];
            #pragma unroll
            for (int fn = 0; fn < 2; ++fn) {
                int rb = wc + fn * 16 + lr;
                bg[fn] = *reinterpret_cast<const short8*>(
                    bsc + rb * 256 + (((ks * 4 + lk) ^ (rb & 15)) << 4));
            }
            #pragma unroll
            for (int fm = 0; fm < 2; ++fm)
                #pragma unroll
                for (int fn = 0; fn < 2; ++fn)
                    acc[fm][fn] = __builtin_amdgcn_mfma_f32_16x16x32_bf16(
                        af[fm][ks], bg[fn], acc[fm][fn], 0, 0, 0);
        }

        // epilogue — C/D map: col = lane&15, row = (lane>>4)*4 + reg [m89/m91]
        #pragma unroll
        for (int fm = 0; fm < 2; ++fm) {
            #pragma unroll
            for (int j = 0; j < 4; ++j) {
                const int ql = wr + fm * 16 + lk * 4 + j;
                if (MODE == 0) {
                    #pragma unroll
                    for (int fn = 0; fn < 2; ++fn) {
                        const int c = cbase + wc + fn * 16 + lr;
                        float s = acc[fm][fn][j];
                        int b = (int)((s + 1.0f) * (NBINS * 0.5f));
                        b = b < 0 ? 0 : (b > NBINS - 1 ? NBINS - 1 : b);
                        binsU8[(size_t)(qbase + ql) * MSAMPLE + c] = (unsigned char)b;
                    }
                } else {
                    const float t_ = thrv[fm][j];
                    const float s0 = acc[fm][0][j], s1 = acc[fm][1][j];
                    if (__any(fmaxf(s0, s1) >= t_)) {
                        #pragma unroll
                        for (int fn = 0; fn < 2; ++fn) {
                            const int c = cbase + wc + fn * 16 + lr;
                            const float s = fn ? s1 : s0;
                            if (c < N && s >= t_) {
                                int qs = (int)((s + 1.0f) * 16384.0f);
                                qs = qs < 0 ? 0 : (qs > 32767 ? 32767 : qs);
                                unsigned key = ((unsigned)qs << QSH)
                                             | (~(unsigned)c & QMASK);
                                int p = atomicAdd(&off_l[ql], 1);   // LDS-local
                                if (p < BCAP)
                                    buckets[((size_t)(qbase + ql) * NGRP + g) * BCAP + p] = key;
                            }
                        }
                    }
                }
            }
        }
        __syncthreads();
        cur ^= 1;
    }
#undef STAGE

    if (MODE == 1) {
        for (int i = tid; i < 64; i += 256)
            cnt2[(qbase + i) * NGRP + g] = min(off_l[i], BCAP);
    }
}

// ---------------------------------------------------------------------------
// thresh with per-wave sub-histograms (identical to R11)
// ---------------------------------------------------------------------------
__global__ __launch_bounds__(256)
void thresh_kernel(const unsigned char* __restrict__ bins, float* __restrict__ thr)
{
    __shared__ int hS[4 * NBINS];
    __shared__ int hA[NBINS];
    __shared__ int hB[NBINS];
    __shared__ int best;
    const int q = blockIdx.x, tid = threadIdx.x;
    const int wv = tid >> 6;
    for (int i = tid; i < 4 * NBINS; i += 256) hS[i] = 0;
    if (tid == 0) best = 0;
    __syncthreads();
    const uint4* bp = reinterpret_cast<const uint4*>(bins + (size_t)q * MSAMPLE);
    int* hw = hS + wv * NBINS;
    for (int i = tid; i < MSAMPLE / 16; i += 256) {
        uint4 v = bp[i];
        unsigned xs[4] = {v.x, v.y, v.z, v.w};
        #pragma unroll
        for (int k = 0; k < 4; ++k) {
            unsigned x = xs[k];
            atomicAdd(&hw[x & 255], 1); x >>= 8;
            atomicAdd(&hw[x & 255], 1); x >>= 8;
            atomicAdd(&hw[x & 255], 1); x >>= 8;
            atomicAdd(&hw[x & 255], 1);
        }
    }
    __syncthreads();
    for (int i = tid; i < NBINS; i += 256)
        hA[i] = hS[i] + hS[NBINS + i] + hS[2 * NBINS + i] + hS[3 * NBINS + i];
    __syncthreads();
    int* src = hA; int* dst = hB;
    for (int off = 1; off < NBINS; off <<= 1) {
        for (int i = tid; i < NBINS; i += 256)
            dst[i] = src[i] + ((i + off < NBINS) ? src[i + off] : 0);
        __syncthreads();
        int* tmp = src; src = dst; dst = tmp;
    }
    for (int i = tid; i < NBINS; i += 256)
        if (src[i] >= TOPK) atomicMax(&best, i);
    __syncthreads();
    if (tid == 0)
        thr[q] = (float)(best - 1) * (2.0f / NBINS) - 1.0f;
}

// ---------------------------------------------------------------------------
// Finalize v4: compact keys UNSORTED -> 256-bin histogram of key>>24 ->
// suffix-sum -> coarse bin b32 of 32nd approx key -> cutq=(b32<<7)-QMARGIN
// (superset of the R11-proven selection) -> LDS-append qualifiers (order-free:
// final sort restores determinism via unique keys) -> exact fp32 rbf -> 256-wide
// u64 bitonic (rbf desc, idx asc = jax.lax.top_k) -> weights, V/e gathers.
// ---------------------------------------------------------------------------
__global__ __launch_bounds__(256)
void finalize_kernel(const unsigned int* __restrict__ buckets, const int* __restrict__ cnt2,
                     const float* __restrict__ Qg, const float* __restrict__ Kg,
                     const float* __restrict__ V, const float* __restrict__ hIn,
                     const float* __restrict__ eIn,
                     float* __restrict__ out, int N)
{
    __shared__ float qv[DDIM];
    __shared__ unsigned sk[SORTN];                 // 4KB compacted keys (unsorted)
    __shared__ unsigned fk[FINEN];                 // 1KB selected keys
    __shared__ unsigned long long sk64[FINEN];     // 2KB exact keys
    __shared__ int hA[NBINS];
    __shared__ int hB[NBINS];
    __shared__ int cnts[NGRP], offs[NGRP];
    __shared__ int wpart[2];
    __shared__ int bestb, nsel;
    __shared__ float selV[TOPK];
    __shared__ int   selI[TOPK];
    __shared__ float wts[TOPK];
    const int q = blockIdx.x, tid = threadIdx.x;

    if (tid < DDIM) qv[tid] = Qg[(size_t)q * DDIM + tid];
    if (tid < NGRP) cnts[tid] = cnt2[q * NGRP + tid];
    for (int i = tid; i < SORTN; i += 256) sk[i] = 0u;
    if (tid < NBINS) hA[tid] = 0;
    if (tid < FINEN) sk64[tid] = 0ull;
    if (tid == 0) { bestb = 0; nsel = 0; }
    __syncthreads();
    // 128-wide inclusive scan: per-wave shfl scan + wave-1 offset
    int cv = 0, xv = 0;
    if (tid < NGRP) {
        cv = cnts[tid];
        xv = cv;
        #pragma unroll
        for (int o = 1; o < 64; o <<= 1) {
            int y = __shfl_up(xv, o);
            if ((tid & 63) >= o) xv += y;
        }
        if ((tid & 63) == 63) wpart[tid >> 6] = xv;
    }
    __syncthreads();
    if (tid < NGRP) {
        int add = (tid >= 64) ? wpart[0] : 0;
        offs[tid] = xv - cv + add;
    }
    __syncthreads();
    for (int flat = tid; flat < NGRP * BCAP; flat += 256) {
        int gg = flat / BCAP, j = flat - gg * BCAP;
        if (j < cnts[gg]) {
            int dst = offs[gg] + j;
            if (dst < SORTN)
                sk[dst] = buckets[((size_t)q * NGRP + gg) * BCAP + j];
        }
    }
    __syncthreads();
    // histogram of coarse approx-sim bins (key>>24 = qs>>7)
    for (int i = tid; i < SORTN; i += 256) {
        unsigned k = sk[i];
        if (k) atomicAdd(&hA[k >> 24], 1);
    }
    __syncthreads();
    // suffix-sum over 256 bins
    {
        int* src = hA; int* dst = hB;
        for (int off = 1; off < NBINS; off <<= 1) {
            for (int i = tid; i < NBINS; i += 256)
                dst[i] = src[i] + ((i + off < NBINS) ? src[i + off] : 0);
            __syncthreads();
            int* tmp = src; src = dst; dst = tmp;
        }
        for (int i = tid; i < NBINS; i += 256)
            if (src[i] >= TOPK) atomicMax(&bestb, i);
    }
    __syncthreads();
    // select: coarse lower bound of 32nd key minus margin (superset of exact cut)
    const unsigned b32q = (unsigned)bestb << 7;
    const unsigned cutq = b32q > QMARGIN ? b32q - QMARGIN : 0u;
    const unsigned cutKey = cutq << QSH;
    for (int i = tid; i < SORTN; i += 256) {
        unsigned k = sk[i];
        if (k != 0u && k >= cutKey) {
            int p = atomicAdd(&nsel, 1);
            if (p < FINEN) fk[p] = k;
        }
    }
    __syncthreads();
    const int m = min(nsel, FINEN);
    // exact fp32 sims for selected: 4 lanes per candidate, 64 in flight
    const int sub = tid & 3, ci = tid >> 2;
    #pragma unroll
    for (int base = 0; base < FINEN; base += 64) {
        int i = base + ci;
        bool act = i < m;
        int c = 0;
        float s = 0.f;
        if (act) {
            c = (int)(~fk[i] & QMASK);
            const float4* k4 = reinterpret_cast<const float4*>(Kg + (size_t)c * DDIM) + sub;
            const float4* q4 = reinterpret_cast<const float4*>(qv) + sub;
            #pragma unroll
            for (int d = 0; d < 8; ++d) {
                float4 kk = k4[d * 4];
                float4 qq = q4[d * 4];
                s = fmaf(qq.x, kk.x, s); s = fmaf(qq.y, kk.y, s);
                s = fmaf(qq.z, kk.z, s); s = fmaf(qq.w, kk.w, s);
            }
        }
        s += __shfl_xor(s, 1); s += __shfl_xor(s, 2);
        if (act && sub == 0) {
            float dist = 2.0f - 2.0f * s;              // reference op order
            float rbf = expf(dist * -2.0f);            // exp(-dist/(2*0.25))
            sk64[i] = ((unsigned long long)__float_as_uint(rbf) << 32)
                    | (unsigned)(~(unsigned)c);        // rbf desc, then idx asc
        }
    }
    __syncthreads();
    // bitonic sort u64 desc, 256 elems, 256 threads
    for (int k = 2; k <= FINEN; k <<= 1) {
        for (int j = k >> 1; j > 0; j >>= 1) {
            int x = tid ^ j;
            if (x > tid) {
                unsigned long long a = sk64[tid], b = sk64[x];
                bool sw = ((tid & k) == 0) ? (a < b) : (a > b);
                if (sw) { sk64[tid] = b; sk64[x] = a; }
            }
            __syncthreads();
        }
    }
    if (tid < TOPK) {
        unsigned long long kk = sk64[tid];
        float rbf = __uint_as_float((unsigned)(kk >> 32));
        int   idx = (int)(~(unsigned)kk);
        selV[tid] = rbf; selI[tid] = idx;
        float lw = logf(rbf + 1e-8f) + logf(hIn[idx] + 1e-8f);
        float mx = lw;
        #pragma unroll
        for (int o = 16; o > 0; o >>= 1) mx = fmaxf(mx, __shfl_xor(mx, o));
        float ex = expf(lw - mx);
        float sm = ex;
        #pragma unroll
        for (int o = 16; o > 0; o >>= 1) sm += __shfl_xor(sm, o);
        wts[tid] = ex / sm;
    }
    __syncthreads();
    {
        float acc = 0.f;
        const int v = tid;
        #pragma unroll
        for (int k = 0; k < TOPK; ++k)
            acc = fmaf(wts[k], V[(size_t)selI[k] * 256 + v], acc);
        out[(size_t)q * 256 + v] = acc;
    }
    const int offE = NQTOT * 256;
    const int offW = offE + NQTOT * 4;
    const int offI = offW + NQTOT * TOPK;
    if (tid < 4) {
        float acc = 0.f;
        #pragma unroll
        for (int k = 0; k < TOPK; ++k)
            acc = fmaf(wts[k], eIn[(size_t)selI[k] * 4 + tid], acc);
        out[offE + q * 4 + tid] = acc;
    }
    if (tid < TOPK) {
        out[offW + q * TOPK + tid] = wts[tid];
        out[offI + q * TOPK + tid] = (float)selI[tid];
    }
}

// ---------------------------------------------------------------------------
extern "C" void kernel_launch(void* const* d_in, const int* in_sizes, int n_in,
                              void* d_out, int out_size, void* d_ws, size_t ws_size,
                              hipStream_t stream)
{
    (void)n_in; (void)out_size; (void)ws_size;
    const float* Qg = (const float*)d_in[0];
    const float* Kg = (const float*)d_in[1];
    const float* Vg = (const float*)d_in[2];
    const float* hg = (const float*)d_in[3];
    const float* eg = (const float*)d_in[4];
    const int N = in_sizes[1] / DDIM;          // 100000

    char* w = (char*)d_ws;
    unsigned short* Kbf = (unsigned short*)w;  w += (size_t)N * DDIM * 2;      // 25.6MB
    unsigned short* Qbf = (unsigned short*)w;  w += (size_t)NQTOT * DDIM * 2;  // 256KB
    float* thr = (float*)w;                    w += NQTOT * 4;                 // 4KB
    int*   cnt2 = (int*)w;                     w += (size_t)NQTOT * NGRP * 4;  // 512KB
    unsigned char* binsU8 = (unsigned char*)w;                                 // 12.58MB
    unsigned int*  buckets = (unsigned int*)w; // aliases binsU8 (sequential lifetimes)

    hipMemsetAsync(cnt2, 0, (size_t)NQTOT * NGRP * 4, stream);

    dim3 blk(256);
    convert_kernel<<<dim3(2048), blk, 0, stream>>>(
        Qg, Kg, Qbf, Kbf, NQTOT * DDIM / 8, N * DDIM / 8);
    gemm_pass<0><<<dim3(MSAMPLE / 64, NQTOT / 64), blk, 0, stream>>>(
        Qbf, Kbf, N, binsU8, nullptr, nullptr, nullptr);
    thresh_kernel<<<dim3(NQTOT), blk, 0, stream>>>(binsU8, thr);
    gemm_pass<1><<<dim3(NGRP, NQTOT / 64), blk, 0, stream>>>(
        Qbf, Kbf, N, nullptr, thr, cnt2, buckets);
    finalize_kernel<<<dim3(NQTOT), blk, 0, stream>>>(
        buckets, cnt2, Qg, Kg, Vg, hg, eg, (float*)d_out, N);
}